// Round 3
// baseline (450.588 us; speedup 1.0000x reference)
//
#include <hip/hip_runtime.h>
#include <stdint.h>

#define LDK 136   // padded LDS K-stride (shorts): byte stride 272 -> b128 frag reads spread evenly

typedef __attribute__((ext_vector_type(4))) float f32x4;
typedef __attribute__((ext_vector_type(8))) short bf16x8;

__device__ inline unsigned short f2bf_rtne(float f) {
    union { float f; unsigned u; } v; v.f = f;
    unsigned u = v.u;
    u += 0x7fffu + ((u >> 16) & 1u);
    return (unsigned short)(u >> 16);
}

// ---------------------------------------------------------------------------
// prep: weight transpose+bf16 cast (W1,W2 -> [n][k]; W3 -> 4x128 dense rows),
// mask decode, num_atoms. grid: 64 blocks x 256.
// ---------------------------------------------------------------------------
__global__ void prep_kernel(const float* __restrict__ relW1, const float* __restrict__ relW2,
                            const float* __restrict__ pwW1, const float* __restrict__ pwW2,
                            const float* __restrict__ relW3, const float* __restrict__ pwW3,
                            const void* __restrict__ maskp,
                            float* __restrict__ maskf, float* __restrict__ na,
                            unsigned short* __restrict__ w1T_rel, unsigned short* __restrict__ w2T_rel,
                            unsigned short* __restrict__ w1T_pw, unsigned short* __restrict__ w2T_pw,
                            unsigned short* __restrict__ w3T_rel, unsigned short* __restrict__ w3T_pw) {
    int t = threadIdx.x;
    const float* srcs[4] = {relW1, relW2, pwW1, pwW2};
    unsigned short* dsts[4] = {w1T_rel, w2T_rel, w1T_pw, w2T_pw};
    int e0 = blockIdx.x * 1024 + t;
#pragma unroll
    for (int i = 0; i < 4; ++i) {
        int e = e0 + i * 256;
        int mat = e >> 14, o = e & 16383;
        int n = o >> 7, k = o & 127;
        dsts[mat][o] = f2bf_rtne(srcs[mat][k * 128 + n]);   // wT[n][k] = W[k][n]
    }
    if (blockIdx.x == 1) {
        // W3^T dense: 4 rows (output k) x 128 cols (hidden), bf16
        for (int i = t; i < 512; i += 256) {
            int r = i >> 7, h = i & 127;
            w3T_rel[i] = f2bf_rtne(relW3[h * 4 + r]);
            w3T_pw[i]  = f2bf_rtne(pwW3[h * 4 + r]);
        }
    }
    if (blockIdx.x == 0) {
        __shared__ int anyb;
        __shared__ float cnt[2];
        if (t == 0) anyb = 0;
        if (t < 2) cnt[t] = 0.f;
        __syncthreads();
        // robust mask dtype detection: bool8 storage has nonzero bytes within the
        // first 1024 bytes (indices 448..511 true); int32 storage is all-zero there.
        const unsigned char* mb = (const unsigned char*)maskp;
        int la = 0;
        for (int i = t; i < 1024; i += 256) la |= mb[i];
        if (la) atomicOr(&anyb, 1);
        __syncthreads();
        bool isbyte = (anyb != 0);
        const int* mi = (const int*)maskp;
        float loc0 = 0.f, loc1 = 0.f;
        for (int i = t; i < 1024; i += 256) {
            int v = isbyte ? (int)mb[i] : mi[i];
            float um = (v != 0) ? 0.f : 1.f;   // unmasked = !masked
            maskf[i] = um;
            if (i < 512) loc0 += um; else loc1 += um;
        }
        atomicAdd(&cnt[0], loc0);
        atomicAdd(&cnt[1], loc1);
        __syncthreads();
        if (t < 2) na[t] = cnt[t];
    }
}

// ---------------------------------------------------------------------------
// fused 3-layer MLP + basis contraction.
// blocks 0..2047: rel path (256 consecutive (b,i,j) rows; fixed (b,i), j-range 256)
//   -> accumulates partial[c] = sum_j mask * sum_k S[j][k]*basis[j][k][c]
// blocks 2048..2051: pw path -> writes S_pw rows.
// 4 waves, 4 tiles of 64 rows, weights W1/W2 in VGPR fragments, W3 in LDS.
// Fully-masked tiles (data-driven, block-uniform) are skipped.
// ---------------------------------------------------------------------------
__global__ __launch_bounds__(256, 3)
void mlp_kernel(const float* __restrict__ Xrel, const float* __restrict__ Xpw,
                const unsigned short* __restrict__ w1T_rel, const unsigned short* __restrict__ w2T_rel,
                const unsigned short* __restrict__ w3T_rel,
                const unsigned short* __restrict__ w1T_pw, const unsigned short* __restrict__ w2T_pw,
                const unsigned short* __restrict__ w3T_pw,
                const float* __restrict__ b1r, const float* __restrict__ b2r, const float* __restrict__ b3r,
                const float* __restrict__ b1p, const float* __restrict__ b2p, const float* __restrict__ b3p,
                const float* __restrict__ rel_basis, const float* __restrict__ maskf,
                float* __restrict__ partials, float* __restrict__ S_pw) {
    __shared__ short xs[64 * LDK];
    __shared__ short hs[2][64 * LDK];
    __shared__ short w3ls[512];
    __shared__ float bs1[128], bs2[128], b3s[4];
    __shared__ float msum[4];
    __shared__ float redp[4][3];

    int t = threadIdx.x;
    int w = t >> 6, lane = t & 63, q = lane >> 4, col = lane & 15;
    bool isrel = blockIdx.x < 2048;

    const float* X = isrel ? Xrel : Xpw;
    const unsigned short* w1T = isrel ? w1T_rel : w1T_pw;
    const unsigned short* w2T = isrel ? w2T_rel : w2T_pw;
    const unsigned short* w3T = isrel ? w3T_rel : w3T_pw;
    const float* b1 = isrel ? b1r : b1p;
    const float* b2 = isrel ? b2r : b2p;
    const float* b3 = isrel ? b3r : b3p;
    long rowbase = isrel ? (long)blockIdx.x * 256 : (long)(blockIdx.x - 2048) * 256;
    // mask base: b*512 + jbase (rel only)
    int mb = isrel ? (((int)(blockIdx.x >> 10)) << 9) | ((blockIdx.x & 1) << 8) : 0;

    if (t < 128) { bs1[t] = b1[t]; bs2[t] = b2[t]; }
    if (t < 4) b3s[t] = b3[t];
    if (t < 128) *(short4*)&w3ls[t * 4] = *(const short4*)&w3T[t * 4];

    // W1/W2 A-fragments: A[n][k], n = base+(lane&15), k = kc*32+(lane>>4)*8+j
    bf16x8 w1f[2][4], w2f[2][4];
#pragma unroll
    for (int tn = 0; tn < 2; ++tn)
#pragma unroll
        for (int kc = 0; kc < 4; ++kc) {
            int n = w * 32 + tn * 16 + col;
            int kk = kc * 32 + q * 8;
            w1f[tn][kc] = *(const bf16x8*)&w1T[n * 128 + kk];
            w2f[tn][kc] = *(const bf16x8*)&w2T[n * 128 + kk];
        }

    int r0 = t >> 5, cg = t & 31;

    // initial prefetch of tile 0 + per-tile activity flags (wave w == tile w rows)
    float4 px[8];
    {
        const float4* Xg = (const float4*)(X + rowbase * 128);
#pragma unroll
        for (int i = 0; i < 8; ++i) px[i] = Xg[(r0 + 8 * i) * 32 + cg];
    }
    {
        float mv = 1.f;
        if (isrel) mv = maskf[mb + w * 64 + lane];
        int act = __any(mv != 0.f);
        if (lane == 0) msum[w] = act ? 1.f : 0.f;
    }
    __syncthreads();   // msum visible; bs/w3ls visible

    if (msum[0] != 0.f) {
#pragma unroll
        for (int i = 0; i < 8; ++i) {
            float4 v = px[i];
            short4 s4 = make_short4((short)f2bf_rtne(v.x), (short)f2bf_rtne(v.y),
                                    (short)f2bf_rtne(v.z), (short)f2bf_rtne(v.w));
            *(short4*)&xs[(r0 + 8 * i) * LDK + cg * 4] = s4;
        }
    }
    __syncthreads();

    float prt0 = 0.f, prt1 = 0.f, prt2 = 0.f;

    for (int tile = 0; tile < 4; ++tile) {
        int hp = tile & 1;
        bool a_cur = msum[tile] != 0.f;
        bool a_nxt = (tile < 3) && (msum[tile + 1] != 0.f);

        if (!a_cur) {           // fully-masked tile: contribute 0; keep staging pipeline alive
            if (a_nxt) {
                const float4* Xg2 = (const float4*)(X + (rowbase + (long)(tile + 1) * 64) * 128);
#pragma unroll
                for (int i = 0; i < 8; ++i) px[i] = Xg2[(r0 + 8 * i) * 32 + cg];
                __syncthreads();   // prior xs readers done
#pragma unroll
                for (int i = 0; i < 8; ++i) {
                    float4 v = px[i];
                    short4 s4 = make_short4((short)f2bf_rtne(v.x), (short)f2bf_rtne(v.y),
                                            (short)f2bf_rtne(v.z), (short)f2bf_rtne(v.w));
                    *(short4*)&xs[(r0 + 8 * i) * LDK + cg * 4] = s4;
                }
                __syncthreads();   // xs visible to next tile
            } else {
                __syncthreads();   // keep hs write/read fencing chain intact
            }
            continue;
        }

        if (a_nxt) {  // prefetch next X tile into regs
            const float4* Xg2 = (const float4*)(X + (rowbase + (long)(tile + 1) * 64) * 128);
#pragma unroll
            for (int i = 0; i < 8; ++i) px[i] = Xg2[(r0 + 8 * i) * 32 + cg];
        }

        // ---- layer 1: D = W1^T · X^T ----
        f32x4 acc[2][4];
#pragma unroll
        for (int tn = 0; tn < 2; ++tn)
#pragma unroll
            for (int tm = 0; tm < 4; ++tm) acc[tn][tm] = (f32x4)(0.f);
#pragma unroll
        for (int kc = 0; kc < 4; ++kc) {
            bf16x8 bf[4];
#pragma unroll
            for (int tm = 0; tm < 4; ++tm)
                bf[tm] = *(const bf16x8*)&xs[(tm * 16 + col) * LDK + kc * 32 + q * 8];
#pragma unroll
            for (int tn = 0; tn < 2; ++tn)
#pragma unroll
                for (int tm = 0; tm < 4; ++tm)
                    acc[tn][tm] = __builtin_amdgcn_mfma_f32_16x16x32_bf16(w1f[tn][kc], bf[tm], acc[tn][tm], 0, 0, 0);
        }

        // epilogue 1: bias+relu -> bf16 -> hs[hp]
#pragma unroll
        for (int tn = 0; tn < 2; ++tn)
#pragma unroll
            for (int tm = 0; tm < 4; ++tm) {
                int n0 = w * 32 + tn * 16 + q * 4;
                int m = tm * 16 + col;
                float4 bb = *(const float4*)&bs1[n0];
                short4 s4 = make_short4(
                    (short)f2bf_rtne(fmaxf(acc[tn][tm][0] + bb.x, 0.f)),
                    (short)f2bf_rtne(fmaxf(acc[tn][tm][1] + bb.y, 0.f)),
                    (short)f2bf_rtne(fmaxf(acc[tn][tm][2] + bb.z, 0.f)),
                    (short)f2bf_rtne(fmaxf(acc[tn][tm][3] + bb.w, 0.f)));
                *(short4*)&hs[hp][m * LDK + n0] = s4;
            }
        __syncthreads();  // AB: xs reads done (restage ok) + hs[hp] H1 visible

        if (a_nxt) {
#pragma unroll
            for (int i = 0; i < 8; ++i) {
                float4 v = px[i];
                short4 s4 = make_short4((short)f2bf_rtne(v.x), (short)f2bf_rtne(v.y),
                                        (short)f2bf_rtne(v.z), (short)f2bf_rtne(v.w));
                *(short4*)&xs[(r0 + 8 * i) * LDK + cg * 4] = s4;
            }
        }

        // ---- layer 2: D = W2^T · H1^T ----
        f32x4 acc2[2][4];
#pragma unroll
        for (int tn = 0; tn < 2; ++tn)
#pragma unroll
            for (int tm = 0; tm < 4; ++tm) acc2[tn][tm] = (f32x4)(0.f);
#pragma unroll
        for (int kc = 0; kc < 4; ++kc) {
            bf16x8 bf[4];
#pragma unroll
            for (int tm = 0; tm < 4; ++tm)
                bf[tm] = *(const bf16x8*)&hs[hp][(tm * 16 + col) * LDK + kc * 32 + q * 8];
#pragma unroll
            for (int tn = 0; tn < 2; ++tn)
#pragma unroll
                for (int tm = 0; tm < 4; ++tm)
                    acc2[tn][tm] = __builtin_amdgcn_mfma_f32_16x16x32_bf16(w2f[tn][kc], bf[tm], acc2[tn][tm], 0, 0, 0);
        }
        __syncthreads();  // C: H1 reads done

        // epilogue 2 -> hs[hp] = H2
#pragma unroll
        for (int tn = 0; tn < 2; ++tn)
#pragma unroll
            for (int tm = 0; tm < 4; ++tm) {
                int n0 = w * 32 + tn * 16 + q * 4;
                int m = tm * 16 + col;
                float4 bb = *(const float4*)&bs2[n0];
                short4 s4 = make_short4(
                    (short)f2bf_rtne(fmaxf(acc2[tn][tm][0] + bb.x, 0.f)),
                    (short)f2bf_rtne(fmaxf(acc2[tn][tm][1] + bb.y, 0.f)),
                    (short)f2bf_rtne(fmaxf(acc2[tn][tm][2] + bb.z, 0.f)),
                    (short)f2bf_rtne(fmaxf(acc2[tn][tm][3] + bb.w, 0.f)));
                *(short4*)&hs[hp][m * LDK + n0] = s4;
            }
        __syncthreads();  // D: H2 visible

        // ---- layer 3: 4 MFMAs/wave (A = W3 rows 0..3, zeros elsewhere) + fusion ----
        {
            f32x4 a3 = (f32x4)(0.f);
#pragma unroll
            for (int kc = 0; kc < 4; ++kc) {
                bf16x8 w3v = (bf16x8)(short)0;
                if (col < 4) w3v = *(const bf16x8*)&w3ls[col * 128 + kc * 32 + q * 8];
                bf16x8 hb = *(const bf16x8*)&hs[hp][(w * 16 + col) * LDK + kc * 32 + q * 8];
                a3 = __builtin_amdgcn_mfma_f32_16x16x32_bf16(w3v, hb, a3, 0, 0, 0);
            }
            if (q == 0) {   // lane col owns data row w*16+col; regs 0..3 = outputs k=0..3
                int rloc = tile * 64 + w * 16 + col;
                float s0 = a3[0] + b3s[0], s1 = a3[1] + b3s[1];
                float s2 = a3[2] + b3s[2], s3 = a3[3] + b3s[3];
                if (isrel) {
                    float m = maskf[mb + rloc];
                    long r = rowbase + rloc;
                    const float4* bp = (const float4*)&rel_basis[r * 12];
                    float4 q0 = bp[0], q1 = bp[1], q2 = bp[2];
                    s0 *= m; s1 *= m; s2 *= m; s3 *= m;
                    prt0 += s0 * q0.x + s1 * q0.w + s2 * q1.z + s3 * q2.y;
                    prt1 += s0 * q0.y + s1 * q1.x + s2 * q1.w + s3 * q2.z;
                    prt2 += s0 * q0.z + s1 * q1.y + s2 * q2.x + s3 * q2.w;
                } else {
                    long r = rowbase + rloc;
                    *(float4*)&S_pw[r * 4] = make_float4(s0, s1, s2, s3);
                }
            }
        }
    }

    if (isrel) {
        // reduce prt over the 16 q==0 lanes of each wave, then across waves
#pragma unroll
        for (int s = 8; s > 0; s >>= 1) {
            prt0 += __shfl_down(prt0, s);
            prt1 += __shfl_down(prt1, s);
            prt2 += __shfl_down(prt2, s);
        }
        if (lane == 0) { redp[w][0] = prt0; redp[w][1] = prt1; redp[w][2] = prt2; }
        __syncthreads();
        if (t < 3)
            partials[blockIdx.x * 3 + t] =
                redp[0][t] + redp[1][t] + redp[2][t] + redp[3][t];
    }
}

// ---------------------------------------------------------------------------
// final: out[bi][c] = (sum_k pwb*S_pw)/na + (partials[2bi]+partials[2bi+1])[c]/na^2
// grid: 8 x 128 (one thread per (b,i))
// ---------------------------------------------------------------------------
__global__ void final_kernel(const float* __restrict__ partials, const float* __restrict__ S_pw,
                             const float* __restrict__ pw_basis, const float* __restrict__ na,
                             float* __restrict__ out) {
    int bi = blockIdx.x * 128 + threadIdx.x;
    if (bi >= 1024) return;
    float NA = na[bi >> 9];
    float4 s = *(const float4*)&S_pw[bi * 4];
    const float* pb = &pw_basis[bi * 12];
#pragma unroll
    for (int c = 0; c < 3; ++c) {
        float rel = partials[(2 * bi) * 3 + c] + partials[(2 * bi + 1) * 3 + c];
        float pw = s.x * pb[c] + s.y * pb[3 + c] + s.z * pb[6 + c] + s.w * pb[9 + c];
        out[bi * 3 + c] = pw / NA + rel / (NA * NA);
    }
}

// ---------------------------------------------------------------------------
extern "C" void kernel_launch(void* const* d_in, const int* in_sizes, int n_in,
                              void* d_out, int out_size, void* d_ws, size_t ws_size,
                              hipStream_t stream) {
    const float* pw_feat   = (const float*)d_in[0];
    const float* rel_feat  = (const float*)d_in[1];
    const float* pw_basis  = (const float*)d_in[2];
    const float* rel_basis = (const float*)d_in[3];
    const float* pw_W1 = (const float*)d_in[4];
    const float* pw_b1 = (const float*)d_in[5];
    const float* pw_W2 = (const float*)d_in[6];
    const float* pw_b2 = (const float*)d_in[7];
    const float* pw_W3 = (const float*)d_in[8];
    const float* pw_b3 = (const float*)d_in[9];
    const float* rel_W1 = (const float*)d_in[10];
    const float* rel_b1 = (const float*)d_in[11];
    const float* rel_W2 = (const float*)d_in[12];
    const float* rel_b2 = (const float*)d_in[13];
    const float* rel_W3 = (const float*)d_in[14];
    const float* rel_b3 = (const float*)d_in[15];
    const void*  maskp  = d_in[16];
    float* out = (float*)d_out;

    char* ws = (char*)d_ws;
    float* maskf = (float*)(ws + 0);                       // 1024 f32
    float* na    = (float*)(ws + 4096);                    // 2 f32
    unsigned short* w1T_rel = (unsigned short*)(ws + 4352);
    unsigned short* w2T_rel = (unsigned short*)(ws + 37120);
    unsigned short* w1T_pw  = (unsigned short*)(ws + 69888);
    unsigned short* w2T_pw  = (unsigned short*)(ws + 102656);
    unsigned short* w3T_rel = (unsigned short*)(ws + 135424);  // 4x128 bf16
    unsigned short* w3T_pw  = (unsigned short*)(ws + 136448);
    float* S_pw     = (float*)(ws + 143616);               // 1024*4 f32
    float* partials = (float*)(ws + 160000);               // 2048*3 f32

    prep_kernel<<<64, 256, 0, stream>>>(rel_W1, rel_W2, pw_W1, pw_W2, rel_W3, pw_W3, maskp,
                                        maskf, na, w1T_rel, w2T_rel, w1T_pw, w2T_pw,
                                        w3T_rel, w3T_pw);
    mlp_kernel<<<2052, 256, 0, stream>>>(rel_feat, pw_feat,
                                         w1T_rel, w2T_rel, w3T_rel,
                                         w1T_pw, w2T_pw, w3T_pw,
                                         rel_b1, rel_b2, rel_b3,
                                         pw_b1, pw_b2, pw_b3,
                                         rel_basis, maskf, partials, S_pw);
    final_kernel<<<8, 128, 0, stream>>>(partials, S_pw, pw_basis, na, out);
}